// Round 2
// baseline (2792.068 us; speedup 1.0000x reference)
//
#include <hip/hip_runtime.h>
#include <hip/hip_bf16.h>

// GCN: out = softmax( GCNConv2( relu( GCNConv1(x) ) ) )
// GCNConv(x) = D^-1/2 (A+I) D^-1/2 (x W) + b
//
// Structure (round 2): CSR-by-dst + GATHER (no float atomics -> deterministic,
// no read-modify-write of output rows), and layer-1 runs in two 64-feature
// halves so peak workspace is ~85 MB (round-0/1 layout overran d_ws and
// corrupted neighboring allocations -> post-timing divergence).
//
//  1. zero deg              (int, N)
//  2. deg[dst]++            (int atomics, deterministic)
//  3. scan -> rowptr, cursor, norm = 1/sqrt(deg+1)   (single block)
//  4. fill csr_src[slot]=src (slot from int atomic on cursor)
//  5. h1a = x @ W1[:,0:64]            -> bufA
//  6. agg1[:,0:64]  = relu(gather)    (self-loop + bias fused)
//  7. h1b = x @ W1[:,64:128]          -> bufA
//  8. agg1[:,64:128]= relu(gather)
//  9. h2  = agg1 @ W2                 -> bufA
// 10. out = softmax(gather)           (self-loop + bias + softmax fused)

#define K_DIM 128

__global__ __launch_bounds__(256) void zero_int(int* p, int n) {
    int i = blockIdx.x * 256 + threadIdx.x;
    if (i < n) p[i] = 0;
}

__global__ __launch_bounds__(256) void deg_count(const int* __restrict__ dst, int E,
                                                 int* __restrict__ deg) {
    int e = blockIdx.x * 256 + threadIdx.x;
    if (e < E) atomicAdd(&deg[dst[e]], 1);
}

// Single-block exclusive scan of deg -> rowptr; also initializes cursor and norm.
__global__ __launch_bounds__(1024) void scan_rowptr(const int* __restrict__ deg,
                                                    int* __restrict__ rowptr,
                                                    int* __restrict__ cursor,
                                                    float* __restrict__ norm, int n) {
    __shared__ int part[1024];
    const int t = threadIdx.x;
    const int chunk = (n + 1023) >> 10;
    const int s = t * chunk;
    const int e = (s + chunk < n) ? (s + chunk) : n;
    int sum = 0;
    for (int i = s; i < e; ++i) sum += deg[i];
    part[t] = sum;
    __syncthreads();
    // Hillis-Steele inclusive scan over 1024 partials
    for (int off = 1; off < 1024; off <<= 1) {
        int v = (t >= off) ? part[t - off] : 0;
        __syncthreads();
        part[t] += v;
        __syncthreads();
    }
    int run = part[t] - sum;  // exclusive prefix of this thread's chunk
    for (int i = s; i < e; ++i) {
        int d = deg[i];
        rowptr[i] = run;
        cursor[i] = run;
        norm[i] = 1.0f / sqrtf((float)(d + 1));   // +1 self-loop
        run += d;
    }
    if (t == 1023) rowptr[n] = part[1023];        // == E
}

__global__ __launch_bounds__(256) void fill_csr(const int* __restrict__ ei, int E,
                                                int* __restrict__ cursor,
                                                int* __restrict__ csr_src) {
    int e = blockIdx.x * 256 + threadIdx.x;
    if (e < E) {
        int s = ei[e];
        int d = ei[E + e];
        int slot = atomicAdd(&cursor[d], 1);
        csr_src[slot] = s;
    }
}

// Tiled fp32 GEMM: H[nrows x 64] = A[nrows x 128] * W[128 x 64], W row stride LDW.
// Block 256 threads = 16x16, tile 64 rows x 64 cols, 4x4 per thread.
// LDS float4-slot XOR swizzle -> b128 reads at worst 2-way aliased (free).
template<int LDW>
__global__ __launch_bounds__(256) void gemm64(
    const float* __restrict__ A,    // [nrows,128]
    const float* __restrict__ W,    // [128,*], row stride LDW, 64 cols used
    float* __restrict__ H,          // [nrows,64]
    int nrows)
{
    __shared__ float Ast[64 * 128];
    __shared__ float Bst[64 * 128];

    const int tid = threadIdx.x;
    const int tx = tid & 15;
    const int ty = tid >> 4;
    const int row0 = blockIdx.x * 64;

    {   // stage A tile: 64 rows x 128 k
        const int kq = tid & 31;
        const int r  = tid >> 5;
        #pragma unroll
        for (int p = 0; p < 8; ++p) {
            int rr = r + p * 8;
            int grow = row0 + rr;
            if (grow > nrows - 1) grow = nrows - 1;   // clamp; store guarded later
            float4 v = *(const float4*)&A[(size_t)grow * K_DIM + kq * 4];
            *(float4*)&Ast[rr * 128 + 4 * (kq ^ (rr & 7))] = v;
        }
    }
    {   // stage B transposed: Bst[col][k]
        const int cq = tid & 15;
        const int kr = tid >> 4;
        #pragma unroll
        for (int p = 0; p < 8; ++p) {
            int k = kr + p * 16;
            float4 v = *(const float4*)&W[(size_t)k * LDW + cq * 4];
            const float* vf = (const float*)&v;
            #pragma unroll
            for (int j = 0; j < 4; ++j) {
                int col = 4 * cq + j;
                Bst[col * 128 + 4 * ((k >> 2) ^ (col & 7)) + (k & 3)] = vf[j];
            }
        }
    }
    __syncthreads();

    float acc[4][4] = {};
    const int aswb = (ty & 1) * 4;
    const int bsw = tx & 7;
    #pragma unroll
    for (int kc = 0; kc < 32; ++kc) {
        float4 a[4], b[4];
        #pragma unroll
        for (int i = 0; i < 4; ++i)
            a[i] = *(const float4*)&Ast[(ty * 4 + i) * 128 + 4 * (kc ^ (aswb + i))];
        #pragma unroll
        for (int j = 0; j < 4; ++j)
            b[j] = *(const float4*)&Bst[(tx + 16 * j) * 128 + 4 * (kc ^ bsw)];
        #pragma unroll
        for (int i = 0; i < 4; ++i)
            #pragma unroll
            for (int j = 0; j < 4; ++j) {
                acc[i][j] = fmaf(a[i].x, b[j].x, acc[i][j]);
                acc[i][j] = fmaf(a[i].y, b[j].y, acc[i][j]);
                acc[i][j] = fmaf(a[i].z, b[j].z, acc[i][j]);
                acc[i][j] = fmaf(a[i].w, b[j].w, acc[i][j]);
            }
    }

    #pragma unroll
    for (int i = 0; i < 4; ++i) {
        int row = row0 + ty * 4 + i;
        if (row < nrows) {
            #pragma unroll
            for (int j = 0; j < 4; ++j)
                H[(size_t)row * 64 + tx + 16 * j] = acc[i][j];
        }
    }
}

// Gather layer-1 half: agg[d, off+lane (stride 128)] =
//   relu( bias[lane] + norm_d^2 * h[d,lane] + sum_e norm[s]*norm_d * h[s,lane] )
// One wave per dst node; h is compact [n x 64].
__global__ __launch_bounds__(256) void gather_relu(
    const int* __restrict__ rowptr, const int* __restrict__ csr_src,
    const float* __restrict__ norm, const float* __restrict__ h,
    const float* __restrict__ bias, float* __restrict__ agg, int n)
{
    const int lane = threadIdx.x & 63;
    const int w = threadIdx.x >> 6;
    const int d = blockIdx.x * 4 + w;
    if (d >= n) return;
    const float nd = norm[d];
    float a = 0.0f;
    const int jb = rowptr[d], je = rowptr[d + 1];
    for (int j = jb; j < je; ++j) {
        const int s = csr_src[j];
        a = fmaf(norm[s] * nd, h[(size_t)s * 64 + lane], a);
    }
    a += fmaf(nd * nd, h[(size_t)d * 64 + lane], bias[lane]);
    agg[(size_t)d * 128 + lane] = fmaxf(a, 0.0f);
}

// Gather layer-2 + fused row softmax (64 cols == 64 lanes).
__global__ __launch_bounds__(256) void gather_softmax(
    const int* __restrict__ rowptr, const int* __restrict__ csr_src,
    const float* __restrict__ norm, const float* __restrict__ h,
    const float* __restrict__ bias, float* __restrict__ out, int n)
{
    const int lane = threadIdx.x & 63;
    const int w = threadIdx.x >> 6;
    const int d = blockIdx.x * 4 + w;
    if (d >= n) return;
    const float nd = norm[d];
    float a = 0.0f;
    const int jb = rowptr[d], je = rowptr[d + 1];
    for (int j = jb; j < je; ++j) {
        const int s = csr_src[j];
        a = fmaf(norm[s] * nd, h[(size_t)s * 64 + lane], a);
    }
    a += fmaf(nd * nd, h[(size_t)d * 64 + lane], bias[lane]);
    float m = a;
    #pragma unroll
    for (int off = 32; off; off >>= 1) m = fmaxf(m, __shfl_xor(m, off, 64));
    float ex = expf(a - m);
    float ssum = ex;
    #pragma unroll
    for (int off = 32; off; off >>= 1) ssum += __shfl_xor(ssum, off, 64);
    out[(size_t)d * 64 + lane] = ex / ssum;
}

extern "C" void kernel_launch(void* const* d_in, const int* in_sizes, int n_in,
                              void* d_out, int out_size, void* d_ws, size_t ws_size,
                              hipStream_t stream) {
    const float* x  = (const float*)d_in[0];
    const int*   ei = (const int*)d_in[1];
    const float* W1 = (const float*)d_in[2];
    const float* b1 = (const float*)d_in[3];
    const float* W2 = (const float*)d_in[4];
    const float* b2 = (const float*)d_in[5];
    float* out = (float*)d_out;

    const int N = in_sizes[0] / K_DIM;     // 100000
    const int E = in_sizes[1] / 2;         // 1600000

    // Workspace layout (peak ~85 MB; keep WELL under ws_size — round-0 OOB
    // writes corrupted neighboring allocations).
    size_t o = 0;
    char* base = (char*)d_ws;
    auto alloc = [&](size_t elems) {
        void* p = base + o;
        o += (elems * 4 + 1023) & ~(size_t)1023;
        return p;
    };
    int*   deg    = (int*)  alloc(N);
    int*   rowptr = (int*)  alloc(N + 1);
    int*   cursor = (int*)  alloc(N);
    float* norm   = (float*)alloc(N);
    int*   csr    = (int*)  alloc(E);
    float* bufA   = (float*)alloc((size_t)N * 64);   // h1-half, then h2
    float* agg1   = (float*)alloc((size_t)N * 128);

    const int nb_n = (N + 255) / 256;
    const int nb_e = (E + 255) / 256;
    const int nb_g = (N + 3) / 4;          // 4 waves/block, 1 wave per node
    const int nb_m = (N + 63) / 64;        // gemm row tiles

    zero_int<<<nb_n, 256, 0, stream>>>(deg, N);
    deg_count<<<nb_e, 256, 0, stream>>>(ei + E, E, deg);
    scan_rowptr<<<1, 1024, 0, stream>>>(deg, rowptr, cursor, norm, N);
    fill_csr<<<nb_e, 256, 0, stream>>>(ei, E, cursor, csr);

    // Layer 1, half 0 (cols 0..63)
    gemm64<128><<<nb_m, 256, 0, stream>>>(x, W1, bufA, N);
    gather_relu<<<nb_g, 256, 0, stream>>>(rowptr, csr, norm, bufA, b1, agg1, N);
    // Layer 1, half 1 (cols 64..127)
    gemm64<128><<<nb_m, 256, 0, stream>>>(x, W1 + 64, bufA, N);
    gather_relu<<<nb_g, 256, 0, stream>>>(rowptr, csr, norm, bufA, b1 + 64, agg1 + 64, N);

    // Layer 2
    gemm64<64><<<nb_m, 256, 0, stream>>>(agg1, W2, bufA, N);
    gather_softmax<<<nb_g, 256, 0, stream>>>(rowptr, csr, norm, bufA, b2, out, N);
}

// Round 3
// 1094.611 us; speedup vs baseline: 2.5507x; 2.5507x over previous
//
#include <hip/hip_runtime.h>
#include <hip/hip_bf16.h>

// GCN: out = softmax( GCNConv2( relu( GCNConv1(x) ) ) )
// GCNConv(x) = D^-1/2 (A+I) D^-1/2 (x W) + b
//
// Round 3: fix gemm64 register spill (R2: VGPR=256, 1.6 GB/dispatch of
// spill traffic, VALUBusy 5%). New microkernel: rows ty*4+i x cols tx*4+j
// (float4 along cols), B staged in natural [k][col] layout (b128, bank-
// minimal), A staged with float4-slot XOR swizzle, k-loop `#pragma unroll 2`
// to bound live registers (~90 VGPR, no spill).

#define K_DIM 128

__global__ __launch_bounds__(256) void zero_int(int* p, int n) {
    int i = blockIdx.x * 256 + threadIdx.x;
    if (i < n) p[i] = 0;
}

__global__ __launch_bounds__(256) void deg_count(const int* __restrict__ dst, int E,
                                                 int* __restrict__ deg) {
    int e = blockIdx.x * 256 + threadIdx.x;
    if (e < E) atomicAdd(&deg[dst[e]], 1);
}

// Single-block exclusive scan of deg -> rowptr; also initializes cursor and norm.
__global__ __launch_bounds__(1024) void scan_rowptr(const int* __restrict__ deg,
                                                    int* __restrict__ rowptr,
                                                    int* __restrict__ cursor,
                                                    float* __restrict__ norm, int n) {
    __shared__ int part[1024];
    const int t = threadIdx.x;
    const int chunk = (n + 1023) >> 10;
    const int s = t * chunk;
    const int e = (s + chunk < n) ? (s + chunk) : n;
    int sum = 0;
    for (int i = s; i < e; ++i) sum += deg[i];
    part[t] = sum;
    __syncthreads();
    for (int off = 1; off < 1024; off <<= 1) {
        int v = (t >= off) ? part[t - off] : 0;
        __syncthreads();
        part[t] += v;
        __syncthreads();
    }
    int run = part[t] - sum;
    for (int i = s; i < e; ++i) {
        int d = deg[i];
        rowptr[i] = run;
        cursor[i] = run;
        norm[i] = 1.0f / sqrtf((float)(d + 1));   // +1 self-loop
        run += d;
    }
    if (t == 1023) rowptr[n] = part[1023];        // == E
}

__global__ __launch_bounds__(256) void fill_csr(const int* __restrict__ ei, int E,
                                                int* __restrict__ cursor,
                                                int* __restrict__ csr_src) {
    int e = blockIdx.x * 256 + threadIdx.x;
    if (e < E) {
        int s = ei[e];
        int d = ei[E + e];
        int slot = atomicAdd(&cursor[d], 1);
        csr_src[slot] = s;
    }
}

// Tiled fp32 GEMM: H[nrows x 64] = A[nrows x 128] * W[128 x 64] (W row stride LDW).
// Block 256 = 16x16 threads; tile 64 rows x 64 cols; thread does rows ty*4+i,
// cols tx*4..tx*4+3. Ast swizzled (2-way reads = free); Bst natural [k][col].
template<int LDW>
__global__ __launch_bounds__(256) void gemm64(
    const float* __restrict__ A,    // [nrows,128]
    const float* __restrict__ W,    // [128,*], row stride LDW, 64 cols used
    float* __restrict__ H,          // [nrows,64]
    int nrows)
{
    __shared__ float Ast[64 * 128];   // [row][k], float4-slot XOR swizzle
    __shared__ float Bst[128 * 64];   // [k][col], natural

    const int tid = threadIdx.x;
    const int tx = tid & 15;
    const int ty = tid >> 4;
    const int row0 = blockIdx.x * 64;

    {   // stage A: 64 rows x 128 k, b128 loads/stores
        const int kq = tid & 31;      // float4 slot along k
        const int r  = tid >> 5;      // 0..7
        #pragma unroll
        for (int p = 0; p < 8; ++p) {
            int rr = r + p * 8;
            int grow = row0 + rr;
            if (grow > nrows - 1) grow = nrows - 1;   // clamp; store guarded later
            float4 v = *(const float4*)&A[(size_t)grow * K_DIM + kq * 4];
            *(float4*)&Ast[rr * 128 + 4 * (kq ^ (rr & 7))] = v;
        }
    }
    {   // stage B: 128 k x 64 cols, natural layout, b128
        const int cq = tid & 15;
        const int kr = tid >> 4;      // 0..15
        #pragma unroll
        for (int p = 0; p < 8; ++p) {
            int k = kr + p * 16;
            *(float4*)&Bst[k * 64 + cq * 4] = *(const float4*)&W[(size_t)k * LDW + cq * 4];
        }
    }
    __syncthreads();

    float acc[4][4] = {};
    #pragma unroll 2                  // bounded unroll: keep ~90 VGPR, no spill
    for (int k0 = 0; k0 < 128; k0 += 4) {
        float4 b[4];
        #pragma unroll
        for (int kk = 0; kk < 4; ++kk)
            b[kk] = *(const float4*)&Bst[(k0 + kk) * 64 + tx * 4];
        #pragma unroll
        for (int i = 0; i < 4; ++i) {
            const int rr = ty * 4 + i;
            float4 a = *(const float4*)&Ast[rr * 128 + 4 * ((k0 >> 2) ^ (rr & 7))];
            #pragma unroll
            for (int j = 0; j < 4; ++j) {
                acc[i][j] = fmaf(a.x, ((const float*)&b[0])[j], acc[i][j]);
                acc[i][j] = fmaf(a.y, ((const float*)&b[1])[j], acc[i][j]);
                acc[i][j] = fmaf(a.z, ((const float*)&b[2])[j], acc[i][j]);
                acc[i][j] = fmaf(a.w, ((const float*)&b[3])[j], acc[i][j]);
            }
        }
    }

    #pragma unroll
    for (int i = 0; i < 4; ++i) {
        int row = row0 + ty * 4 + i;
        if (row < nrows) {
            float4 o = make_float4(acc[i][0], acc[i][1], acc[i][2], acc[i][3]);
            *(float4*)&H[(size_t)row * 64 + tx * 4] = o;
        }
    }
}

// Gather layer-1 half: agg[d, lane (row stride 128)] =
//   relu( bias[lane] + norm_d^2 * h[d,lane] + sum_e norm[s]*norm_d * h[s,lane] )
// One wave per dst node; h is compact [n x 64].
__global__ __launch_bounds__(256) void gather_relu(
    const int* __restrict__ rowptr, const int* __restrict__ csr_src,
    const float* __restrict__ norm, const float* __restrict__ h,
    const float* __restrict__ bias, float* __restrict__ agg, int n)
{
    const int lane = threadIdx.x & 63;
    const int w = threadIdx.x >> 6;
    const int d = blockIdx.x * 4 + w;
    if (d >= n) return;
    const float nd = norm[d];
    float a = 0.0f;
    const int jb = rowptr[d], je = rowptr[d + 1];
    for (int j = jb; j < je; ++j) {
        const int s = csr_src[j];
        a = fmaf(norm[s] * nd, h[(size_t)s * 64 + lane], a);
    }
    a += fmaf(nd * nd, h[(size_t)d * 64 + lane], bias[lane]);
    agg[(size_t)d * 128 + lane] = fmaxf(a, 0.0f);
}

// Gather layer-2 + fused row softmax (64 cols == 64 lanes).
__global__ __launch_bounds__(256) void gather_softmax(
    const int* __restrict__ rowptr, const int* __restrict__ csr_src,
    const float* __restrict__ norm, const float* __restrict__ h,
    const float* __restrict__ bias, float* __restrict__ out, int n)
{
    const int lane = threadIdx.x & 63;
    const int w = threadIdx.x >> 6;
    const int d = blockIdx.x * 4 + w;
    if (d >= n) return;
    const float nd = norm[d];
    float a = 0.0f;
    const int jb = rowptr[d], je = rowptr[d + 1];
    for (int j = jb; j < je; ++j) {
        const int s = csr_src[j];
        a = fmaf(norm[s] * nd, h[(size_t)s * 64 + lane], a);
    }
    a += fmaf(nd * nd, h[(size_t)d * 64 + lane], bias[lane]);
    float m = a;
    #pragma unroll
    for (int off = 32; off; off >>= 1) m = fmaxf(m, __shfl_xor(m, off, 64));
    float ex = expf(a - m);
    float ssum = ex;
    #pragma unroll
    for (int off = 32; off; off >>= 1) ssum += __shfl_xor(ssum, off, 64);
    out[(size_t)d * 64 + lane] = ex / ssum;
}

extern "C" void kernel_launch(void* const* d_in, const int* in_sizes, int n_in,
                              void* d_out, int out_size, void* d_ws, size_t ws_size,
                              hipStream_t stream) {
    const float* x  = (const float*)d_in[0];
    const int*   ei = (const int*)d_in[1];
    const float* W1 = (const float*)d_in[2];
    const float* b1 = (const float*)d_in[3];
    const float* W2 = (const float*)d_in[4];
    const float* b2 = (const float*)d_in[5];
    float* out = (float*)d_out;

    const int N = in_sizes[0] / K_DIM;     // 100000
    const int E = in_sizes[1] / 2;         // 1600000

    // Workspace layout (peak ~85 MB)
    size_t o = 0;
    char* base = (char*)d_ws;
    auto alloc = [&](size_t elems) {
        void* p = base + o;
        o += (elems * 4 + 1023) & ~(size_t)1023;
        return p;
    };
    int*   deg    = (int*)  alloc(N);
    int*   rowptr = (int*)  alloc(N + 1);
    int*   cursor = (int*)  alloc(N);
    float* norm   = (float*)alloc(N);
    int*   csr    = (int*)  alloc(E);
    float* bufA   = (float*)alloc((size_t)N * 64);   // h1-half, then h2
    float* agg1   = (float*)alloc((size_t)N * 128);

    const int nb_n = (N + 255) / 256;
    const int nb_e = (E + 255) / 256;
    const int nb_g = (N + 3) / 4;          // 4 waves/block, 1 wave per node
    const int nb_m = (N + 63) / 64;        // gemm row tiles

    zero_int<<<nb_n, 256, 0, stream>>>(deg, N);
    deg_count<<<nb_e, 256, 0, stream>>>(ei + E, E, deg);
    scan_rowptr<<<1, 1024, 0, stream>>>(deg, rowptr, cursor, norm, N);
    fill_csr<<<nb_e, 256, 0, stream>>>(ei, E, cursor, csr);

    // Layer 1, half 0 (cols 0..63)
    gemm64<128><<<nb_m, 256, 0, stream>>>(x, W1, bufA, N);
    gather_relu<<<nb_g, 256, 0, stream>>>(rowptr, csr, norm, bufA, b1, agg1, N);
    // Layer 1, half 1 (cols 64..127)
    gemm64<128><<<nb_m, 256, 0, stream>>>(x, W1 + 64, bufA, N);
    gather_relu<<<nb_g, 256, 0, stream>>>(rowptr, csr, norm, bufA, b1 + 64, agg1 + 64, N);

    // Layer 2
    gemm64<64><<<nb_m, 256, 0, stream>>>(agg1, W2, bufA, N);
    gather_softmax<<<nb_g, 256, 0, stream>>>(rowptr, csr, norm, bufA, b2, out, N);
}

// Round 4
// 596.705 us; speedup vs baseline: 4.6791x; 1.8344x over previous
//
#include <hip/hip_runtime.h>
#include <hip/hip_bf16.h>

// GCN: out = softmax( GCNConv2( relu( GCNConv1(x) ) ) )
// GCNConv(x) = D^-1/2 (A+I) D^-1/2 (x W) + b
//
// Round 4:
//  (a) scan_rowptr was 278 us on ONE block (25% of total, 0.14% occupancy).
//      Replaced with 3-kernel parallel scan: block_sums -> scan_bsums ->
//      scan_write (all multi-block, ~10 us total).
//  (b) gather loops had a serial dependent-load chain per edge
//      (csr_src[j] -> norm[s] -> h[s,:]). Now lanes preload 64 indices+norms
//      per chunk (2 vector loads), broadcast via shfl, and the inner loop
//      issues 2 independent h-gathers per iteration (dual accumulators).

#define K_DIM 128

__global__ __launch_bounds__(256) void zero_int(int* p, int n) {
    int i = blockIdx.x * 256 + threadIdx.x;
    if (i < n) p[i] = 0;
}

__global__ __launch_bounds__(256) void deg_count(const int* __restrict__ dst, int E,
                                                 int* __restrict__ deg) {
    int e = blockIdx.x * 256 + threadIdx.x;
    if (e < E) atomicAdd(&deg[dst[e]], 1);
}

// ---- parallel exclusive scan of deg (N elements) ----
// Pass 1: per-block (256 elems) sums.
__global__ __launch_bounds__(256) void block_sums(const int* __restrict__ deg, int n,
                                                  int* __restrict__ bsum) {
    const int i = blockIdx.x * 256 + threadIdx.x;
    int v = (i < n) ? deg[i] : 0;
    #pragma unroll
    for (int off = 32; off; off >>= 1) v += __shfl_xor(v, off, 64);
    __shared__ int ws[4];
    const int lane = threadIdx.x & 63, wid = threadIdx.x >> 6;
    if (lane == 0) ws[wid] = v;
    __syncthreads();
    if (threadIdx.x == 0) bsum[blockIdx.x] = ws[0] + ws[1] + ws[2] + ws[3];
}

// Pass 2: single block scans the (<=1024*chunk) block sums in place (exclusive).
__global__ __launch_bounds__(1024) void scan_bsums(int* __restrict__ bsum, int nb,
                                                   int* __restrict__ rowptr, int n) {
    __shared__ int part[1024];
    const int t = threadIdx.x;
    const int chunk = (nb + 1023) >> 10;
    const int s = t * chunk;
    const int e = (s + chunk < nb) ? (s + chunk) : nb;
    int sum = 0;
    for (int i = s; i < e; ++i) sum += bsum[i];
    part[t] = sum;
    __syncthreads();
    for (int off = 1; off < 1024; off <<= 1) {
        int u = (t >= off) ? part[t - off] : 0;
        __syncthreads();
        part[t] += u;
        __syncthreads();
    }
    int run = part[t] - sum;
    for (int i = s; i < e; ++i) { int v = bsum[i]; bsum[i] = run; run += v; }
    if (t == 1023) rowptr[n] = part[1023];     // == E
}

// Pass 3: block-local exclusive scan + block offset; writes rowptr/cursor/norm.
__global__ __launch_bounds__(256) void scan_write(const int* __restrict__ deg,
                                                  const int* __restrict__ bsum, int n,
                                                  int* __restrict__ rowptr,
                                                  int* __restrict__ cursor,
                                                  float* __restrict__ norm) {
    const int i = blockIdx.x * 256 + threadIdx.x;
    const int lane = threadIdx.x & 63, wid = threadIdx.x >> 6;
    const int v = (i < n) ? deg[i] : 0;
    int inc = v;
    #pragma unroll
    for (int off = 1; off < 64; off <<= 1) {
        int u = __shfl_up(inc, off, 64);
        if (lane >= off) inc += u;
    }
    __shared__ int wsum[4];
    if (lane == 63) wsum[wid] = inc;
    __syncthreads();
    int woff = 0;
    for (int w = 0; w < wid; ++w) woff += wsum[w];
    if (i < n) {
        const int excl = bsum[blockIdx.x] + woff + inc - v;
        rowptr[i] = excl;
        cursor[i] = excl;
        norm[i] = rsqrtf((float)(v + 1));      // +1 self-loop
    }
}

__global__ __launch_bounds__(256) void fill_csr(const int* __restrict__ ei, int E,
                                                int* __restrict__ cursor,
                                                int* __restrict__ csr_src) {
    int e = blockIdx.x * 256 + threadIdx.x;
    if (e < E) {
        int s = ei[e];
        int d = ei[E + e];
        int slot = atomicAdd(&cursor[d], 1);
        csr_src[slot] = s;
    }
}

// Tiled fp32 GEMM: H[nrows x 64] = A[nrows x 128] * W[128 x 64] (W row stride LDW).
template<int LDW>
__global__ __launch_bounds__(256) void gemm64(
    const float* __restrict__ A, const float* __restrict__ W,
    float* __restrict__ H, int nrows)
{
    __shared__ float Ast[64 * 128];   // [row][k], float4-slot XOR swizzle
    __shared__ float Bst[128 * 64];   // [k][col], natural

    const int tid = threadIdx.x;
    const int tx = tid & 15;
    const int ty = tid >> 4;
    const int row0 = blockIdx.x * 64;

    {   // stage A
        const int kq = tid & 31;
        const int r  = tid >> 5;
        #pragma unroll
        for (int p = 0; p < 8; ++p) {
            int rr = r + p * 8;
            int grow = row0 + rr;
            if (grow > nrows - 1) grow = nrows - 1;
            float4 v = *(const float4*)&A[(size_t)grow * K_DIM + kq * 4];
            *(float4*)&Ast[rr * 128 + 4 * (kq ^ (rr & 7))] = v;
        }
    }
    {   // stage B
        const int cq = tid & 15;
        const int kr = tid >> 4;
        #pragma unroll
        for (int p = 0; p < 8; ++p) {
            int k = kr + p * 16;
            *(float4*)&Bst[k * 64 + cq * 4] = *(const float4*)&W[(size_t)k * LDW + cq * 4];
        }
    }
    __syncthreads();

    float acc[4][4] = {};
    #pragma unroll 2
    for (int k0 = 0; k0 < 128; k0 += 4) {
        float4 b[4];
        #pragma unroll
        for (int kk = 0; kk < 4; ++kk)
            b[kk] = *(const float4*)&Bst[(k0 + kk) * 64 + tx * 4];
        #pragma unroll
        for (int i = 0; i < 4; ++i) {
            const int rr = ty * 4 + i;
            float4 a = *(const float4*)&Ast[rr * 128 + 4 * ((k0 >> 2) ^ (rr & 7))];
            #pragma unroll
            for (int j = 0; j < 4; ++j) {
                acc[i][j] = fmaf(a.x, ((const float*)&b[0])[j], acc[i][j]);
                acc[i][j] = fmaf(a.y, ((const float*)&b[1])[j], acc[i][j]);
                acc[i][j] = fmaf(a.z, ((const float*)&b[2])[j], acc[i][j]);
                acc[i][j] = fmaf(a.w, ((const float*)&b[3])[j], acc[i][j]);
            }
        }
    }

    #pragma unroll
    for (int i = 0; i < 4; ++i) {
        int row = row0 + ty * 4 + i;
        if (row < nrows) {
            float4 o = make_float4(acc[i][0], acc[i][1], acc[i][2], acc[i][3]);
            *(float4*)&H[(size_t)row * 64 + tx * 4] = o;
        }
    }
}

// Edge accumulation core for one dst node d (one wave): returns
// sum_e norm[s]*nd * h[s,lane], with lane-parallel index/norm preload and
// 2-way load overlap.
__device__ __forceinline__ float edge_accum(
    const int* __restrict__ csr_src, const float* __restrict__ norm,
    const float* __restrict__ h, int jb, int je, float nd, int lane)
{
    float a0 = 0.0f, a1 = 0.0f;
    for (int j0 = jb; j0 < je; j0 += 64) {
        const int cnt = (je - j0 < 64) ? (je - j0) : 64;
        int   sidx = 0;
        float ns   = 0.0f;
        if (lane < cnt) {
            sidx = csr_src[j0 + lane];
            ns   = norm[sidx];
        }
        int t = 0;
        for (; t + 1 < cnt; t += 2) {
            const int   s0 = __shfl(sidx, t, 64);
            const int   s1 = __shfl(sidx, t + 1, 64);
            const float c0 = __shfl(ns, t, 64) * nd;
            const float c1 = __shfl(ns, t + 1, 64) * nd;
            const float v0 = h[(size_t)s0 * 64 + lane];
            const float v1 = h[(size_t)s1 * 64 + lane];
            a0 = fmaf(c0, v0, a0);
            a1 = fmaf(c1, v1, a1);
        }
        if (t < cnt) {
            const int   s0 = __shfl(sidx, t, 64);
            const float c0 = __shfl(ns, t, 64) * nd;
            a0 = fmaf(c0, h[(size_t)s0 * 64 + lane], a0);
        }
    }
    return a0 + a1;
}

// Gather layer-1 half: agg[d, lane (row stride 128)] = relu(bias + self + edges)
__global__ __launch_bounds__(256) void gather_relu(
    const int* __restrict__ rowptr, const int* __restrict__ csr_src,
    const float* __restrict__ norm, const float* __restrict__ h,
    const float* __restrict__ bias, float* __restrict__ agg, int n)
{
    const int lane = threadIdx.x & 63;
    const int w = threadIdx.x >> 6;
    const int d = blockIdx.x * 4 + w;
    if (d >= n) return;
    const float nd = norm[d];
    float a = edge_accum(csr_src, norm, h, rowptr[d], rowptr[d + 1], nd, lane);
    a += fmaf(nd * nd, h[(size_t)d * 64 + lane], bias[lane]);
    agg[(size_t)d * 128 + lane] = fmaxf(a, 0.0f);
}

// Gather layer-2 + fused row softmax (64 cols == 64 lanes).
__global__ __launch_bounds__(256) void gather_softmax(
    const int* __restrict__ rowptr, const int* __restrict__ csr_src,
    const float* __restrict__ norm, const float* __restrict__ h,
    const float* __restrict__ bias, float* __restrict__ out, int n)
{
    const int lane = threadIdx.x & 63;
    const int w = threadIdx.x >> 6;
    const int d = blockIdx.x * 4 + w;
    if (d >= n) return;
    const float nd = norm[d];
    float a = edge_accum(csr_src, norm, h, rowptr[d], rowptr[d + 1], nd, lane);
    a += fmaf(nd * nd, h[(size_t)d * 64 + lane], bias[lane]);
    float m = a;
    #pragma unroll
    for (int off = 32; off; off >>= 1) m = fmaxf(m, __shfl_xor(m, off, 64));
    float ex = expf(a - m);
    float ssum = ex;
    #pragma unroll
    for (int off = 32; off; off >>= 1) ssum += __shfl_xor(ssum, off, 64);
    out[(size_t)d * 64 + lane] = ex / ssum;
}

extern "C" void kernel_launch(void* const* d_in, const int* in_sizes, int n_in,
                              void* d_out, int out_size, void* d_ws, size_t ws_size,
                              hipStream_t stream) {
    const float* x  = (const float*)d_in[0];
    const int*   ei = (const int*)d_in[1];
    const float* W1 = (const float*)d_in[2];
    const float* b1 = (const float*)d_in[3];
    const float* W2 = (const float*)d_in[4];
    const float* b2 = (const float*)d_in[5];
    float* out = (float*)d_out;

    const int N = in_sizes[0] / K_DIM;     // 100000
    const int E = in_sizes[1] / 2;         // 1600000

    // Workspace layout (peak ~85 MB)
    size_t o = 0;
    char* base = (char*)d_ws;
    auto alloc = [&](size_t elems) {
        void* p = base + o;
        o += (elems * 4 + 1023) & ~(size_t)1023;
        return p;
    };
    const int nb_n = (N + 255) / 256;
    int*   deg    = (int*)  alloc(N);
    int*   rowptr = (int*)  alloc(N + 1);
    int*   cursor = (int*)  alloc(N);
    float* norm   = (float*)alloc(N);
    int*   bsum   = (int*)  alloc(nb_n);
    int*   csr    = (int*)  alloc(E);
    float* bufA   = (float*)alloc((size_t)N * 64);   // h1-half, then h2
    float* agg1   = (float*)alloc((size_t)N * 128);

    const int nb_e = (E + 255) / 256;
    const int nb_g = (N + 3) / 4;          // 4 waves/block, 1 wave per node
    const int nb_m = (N + 63) / 64;        // gemm row tiles

    zero_int<<<nb_n, 256, 0, stream>>>(deg, N);
    deg_count<<<nb_e, 256, 0, stream>>>(ei + E, E, deg);
    block_sums<<<nb_n, 256, 0, stream>>>(deg, N, bsum);
    scan_bsums<<<1, 1024, 0, stream>>>(bsum, nb_n, rowptr, N);
    scan_write<<<nb_n, 256, 0, stream>>>(deg, bsum, N, rowptr, cursor, norm);
    fill_csr<<<nb_e, 256, 0, stream>>>(ei, E, cursor, csr);

    // Layer 1, half 0 (cols 0..63)
    gemm64<128><<<nb_m, 256, 0, stream>>>(x, W1, bufA, N);
    gather_relu<<<nb_g, 256, 0, stream>>>(rowptr, csr, norm, bufA, b1, agg1, N);
    // Layer 1, half 1 (cols 64..128)
    gemm64<128><<<nb_m, 256, 0, stream>>>(x, W1 + 64, bufA, N);
    gather_relu<<<nb_g, 256, 0, stream>>>(rowptr, csr, norm, bufA, b1 + 64, agg1 + 64, N);

    // Layer 2
    gemm64<64><<<nb_m, 256, 0, stream>>>(agg1, W2, bufA, N);
    gather_softmax<<<nb_g, 256, 0, stream>>>(rowptr, csr, norm, bufA, b2, out, N);
}

// Round 5
// 516.369 us; speedup vs baseline: 5.4071x; 1.1556x over previous
//
#include <hip/hip_runtime.h>
#include <hip/hip_bf16.h>

// GCN: out = softmax( GCNConv2( relu( GCNConv1(x) ) ) )
// GCNConv(x) = D^-1/2 (A+I) D^-1/2 (x W) + b
//
// Round 5:
//  (a) fill_csr was write-amplification-bound: 1.6M random 4B stores ->
//      106 MB of partial-line write-backs (measured), 130 us. Now XCD-range
//      bucketed: block b handles dst range (b&7) [12.5k nodes; csr segment
//      0.8 MB fits one XCD L2], scans edge chunk b>>3. All writers of a csr
//      segment share an XCD (blockIdx%8 locality heuristic) -> lines fill
//      fully in L2 -> ~7 MB HBM writes. The 8x edge-list re-read is
//      LLC-absorbed (adjacent blocks read the same chunk near-simultaneously).
//  (b) same transform for deg_count.
//  (c) gather inner loop ILP 2 -> 4 independent h-row loads per iteration.

#define K_DIM 128

__global__ __launch_bounds__(256) void zero_int(int* p, int n) {
    int i = blockIdx.x * 256 + threadIdx.x;
    if (i < n) p[i] = 0;
}

// XCD-bucketed degree count: block handles dst range (blockIdx&7).
__global__ __launch_bounds__(256) void deg_count_x(const int* __restrict__ dst, int E,
                                                   int nper, int* __restrict__ deg) {
    const int r = blockIdx.x & 7;
    const int e = (blockIdx.x >> 3) * 256 + threadIdx.x;
    if (e >= E) return;
    const int d = dst[e];
    if ((unsigned)(d - r * nper) < (unsigned)nper) atomicAdd(&deg[d], 1);
}

// ---- parallel exclusive scan of deg (N elements) ----
__global__ __launch_bounds__(256) void block_sums(const int* __restrict__ deg, int n,
                                                  int* __restrict__ bsum) {
    const int i = blockIdx.x * 256 + threadIdx.x;
    int v = (i < n) ? deg[i] : 0;
    #pragma unroll
    for (int off = 32; off; off >>= 1) v += __shfl_xor(v, off, 64);
    __shared__ int ws[4];
    const int lane = threadIdx.x & 63, wid = threadIdx.x >> 6;
    if (lane == 0) ws[wid] = v;
    __syncthreads();
    if (threadIdx.x == 0) bsum[blockIdx.x] = ws[0] + ws[1] + ws[2] + ws[3];
}

__global__ __launch_bounds__(1024) void scan_bsums(int* __restrict__ bsum, int nb,
                                                   int* __restrict__ rowptr, int n) {
    __shared__ int part[1024];
    const int t = threadIdx.x;
    const int chunk = (nb + 1023) >> 10;
    const int s = t * chunk;
    const int e = (s + chunk < nb) ? (s + chunk) : nb;
    int sum = 0;
    for (int i = s; i < e; ++i) sum += bsum[i];
    part[t] = sum;
    __syncthreads();
    for (int off = 1; off < 1024; off <<= 1) {
        int u = (t >= off) ? part[t - off] : 0;
        __syncthreads();
        part[t] += u;
        __syncthreads();
    }
    int run = part[t] - sum;
    for (int i = s; i < e; ++i) { int v = bsum[i]; bsum[i] = run; run += v; }
    if (t == 1023) rowptr[n] = part[1023];     // == E
}

__global__ __launch_bounds__(256) void scan_write(const int* __restrict__ deg,
                                                  const int* __restrict__ bsum, int n,
                                                  int* __restrict__ rowptr,
                                                  int* __restrict__ cursor,
                                                  float* __restrict__ norm) {
    const int i = blockIdx.x * 256 + threadIdx.x;
    const int lane = threadIdx.x & 63, wid = threadIdx.x >> 6;
    const int v = (i < n) ? deg[i] : 0;
    int inc = v;
    #pragma unroll
    for (int off = 1; off < 64; off <<= 1) {
        int u = __shfl_up(inc, off, 64);
        if (lane >= off) inc += u;
    }
    __shared__ int wsum[4];
    if (lane == 63) wsum[wid] = inc;
    __syncthreads();
    int woff = 0;
    for (int w = 0; w < wid; ++w) woff += wsum[w];
    if (i < n) {
        const int excl = bsum[blockIdx.x] + woff + inc - v;
        rowptr[i] = excl;
        cursor[i] = excl;
        norm[i] = rsqrtf((float)(v + 1));      // +1 self-loop
    }
}

// XCD-bucketed CSR fill: block handles dst range (blockIdx&7), edge chunk
// blockIdx>>3. csr/cursor segments for a range stay resident in one XCD L2.
__global__ __launch_bounds__(256) void fill_csr_x(const int* __restrict__ ei, int E,
                                                  int nper,
                                                  int* __restrict__ cursor,
                                                  int* __restrict__ csr_src) {
    const int r = blockIdx.x & 7;
    const int e = (blockIdx.x >> 3) * 256 + threadIdx.x;
    if (e >= E) return;
    const int d = ei[E + e];
    if ((unsigned)(d - r * nper) < (unsigned)nper) {
        const int s = ei[e];
        const int slot = atomicAdd(&cursor[d], 1);
        csr_src[slot] = s;
    }
}

// Tiled fp32 GEMM: H[nrows x 64] = A[nrows x 128] * W[128 x 64] (W row stride LDW).
template<int LDW>
__global__ __launch_bounds__(256) void gemm64(
    const float* __restrict__ A, const float* __restrict__ W,
    float* __restrict__ H, int nrows)
{
    __shared__ float Ast[64 * 128];   // [row][k], float4-slot XOR swizzle
    __shared__ float Bst[128 * 64];   // [k][col], natural

    const int tid = threadIdx.x;
    const int tx = tid & 15;
    const int ty = tid >> 4;
    const int row0 = blockIdx.x * 64;

    {   // stage A
        const int kq = tid & 31;
        const int r  = tid >> 5;
        #pragma unroll
        for (int p = 0; p < 8; ++p) {
            int rr = r + p * 8;
            int grow = row0 + rr;
            if (grow > nrows - 1) grow = nrows - 1;
            float4 v = *(const float4*)&A[(size_t)grow * K_DIM + kq * 4];
            *(float4*)&Ast[rr * 128 + 4 * (kq ^ (rr & 7))] = v;
        }
    }
    {   // stage B
        const int cq = tid & 15;
        const int kr = tid >> 4;
        #pragma unroll
        for (int p = 0; p < 8; ++p) {
            int k = kr + p * 16;
            *(float4*)&Bst[k * 64 + cq * 4] = *(const float4*)&W[(size_t)k * LDW + cq * 4];
        }
    }
    __syncthreads();

    float acc[4][4] = {};
    #pragma unroll 2
    for (int k0 = 0; k0 < 128; k0 += 4) {
        float4 b[4];
        #pragma unroll
        for (int kk = 0; kk < 4; ++kk)
            b[kk] = *(const float4*)&Bst[(k0 + kk) * 64 + tx * 4];
        #pragma unroll
        for (int i = 0; i < 4; ++i) {
            const int rr = ty * 4 + i;
            float4 a = *(const float4*)&Ast[rr * 128 + 4 * ((k0 >> 2) ^ (rr & 7))];
            #pragma unroll
            for (int j = 0; j < 4; ++j) {
                acc[i][j] = fmaf(a.x, ((const float*)&b[0])[j], acc[i][j]);
                acc[i][j] = fmaf(a.y, ((const float*)&b[1])[j], acc[i][j]);
                acc[i][j] = fmaf(a.z, ((const float*)&b[2])[j], acc[i][j]);
                acc[i][j] = fmaf(a.w, ((const float*)&b[3])[j], acc[i][j]);
            }
        }
    }

    #pragma unroll
    for (int i = 0; i < 4; ++i) {
        int row = row0 + ty * 4 + i;
        if (row < nrows) {
            float4 o = make_float4(acc[i][0], acc[i][1], acc[i][2], acc[i][3]);
            *(float4*)&H[(size_t)row * 64 + tx * 4] = o;
        }
    }
}

// Edge accumulation for one dst node (one wave): lanes preload 64 indices +
// norms, broadcast via shfl; inner loop issues 4 independent h-row loads.
__device__ __forceinline__ float edge_accum(
    const int* __restrict__ csr_src, const float* __restrict__ norm,
    const float* __restrict__ h, int jb, int je, float nd, int lane)
{
    float a0 = 0.0f, a1 = 0.0f, a2 = 0.0f, a3 = 0.0f;
    for (int j0 = jb; j0 < je; j0 += 64) {
        const int cnt = (je - j0 < 64) ? (je - j0) : 64;
        int   sidx = 0;
        float ns   = 0.0f;
        if (lane < cnt) {
            sidx = csr_src[j0 + lane];
            ns   = norm[sidx];
        }
        int t = 0;
        for (; t + 3 < cnt; t += 4) {
            const int   s0 = __shfl(sidx, t, 64);
            const int   s1 = __shfl(sidx, t + 1, 64);
            const int   s2 = __shfl(sidx, t + 2, 64);
            const int   s3 = __shfl(sidx, t + 3, 64);
            const float c0 = __shfl(ns, t, 64) * nd;
            const float c1 = __shfl(ns, t + 1, 64) * nd;
            const float c2 = __shfl(ns, t + 2, 64) * nd;
            const float c3 = __shfl(ns, t + 3, 64) * nd;
            const float v0 = h[(size_t)s0 * 64 + lane];
            const float v1 = h[(size_t)s1 * 64 + lane];
            const float v2 = h[(size_t)s2 * 64 + lane];
            const float v3 = h[(size_t)s3 * 64 + lane];
            a0 = fmaf(c0, v0, a0);
            a1 = fmaf(c1, v1, a1);
            a2 = fmaf(c2, v2, a2);
            a3 = fmaf(c3, v3, a3);
        }
        for (; t < cnt; ++t) {
            const int   s0 = __shfl(sidx, t, 64);
            const float c0 = __shfl(ns, t, 64) * nd;
            a0 = fmaf(c0, h[(size_t)s0 * 64 + lane], a0);
        }
    }
    return (a0 + a1) + (a2 + a3);
}

// Gather layer-1 half: agg[d, lane (row stride 128)] = relu(bias + self + edges)
__global__ __launch_bounds__(256) void gather_relu(
    const int* __restrict__ rowptr, const int* __restrict__ csr_src,
    const float* __restrict__ norm, const float* __restrict__ h,
    const float* __restrict__ bias, float* __restrict__ agg, int n)
{
    const int lane = threadIdx.x & 63;
    const int w = threadIdx.x >> 6;
    const int d = blockIdx.x * 4 + w;
    if (d >= n) return;
    const float nd = norm[d];
    float a = edge_accum(csr_src, norm, h, rowptr[d], rowptr[d + 1], nd, lane);
    a += fmaf(nd * nd, h[(size_t)d * 64 + lane], bias[lane]);
    agg[(size_t)d * 128 + lane] = fmaxf(a, 0.0f);
}

// Gather layer-2 + fused row softmax (64 cols == 64 lanes).
__global__ __launch_bounds__(256) void gather_softmax(
    const int* __restrict__ rowptr, const int* __restrict__ csr_src,
    const float* __restrict__ norm, const float* __restrict__ h,
    const float* __restrict__ bias, float* __restrict__ out, int n)
{
    const int lane = threadIdx.x & 63;
    const int w = threadIdx.x >> 6;
    const int d = blockIdx.x * 4 + w;
    if (d >= n) return;
    const float nd = norm[d];
    float a = edge_accum(csr_src, norm, h, rowptr[d], rowptr[d + 1], nd, lane);
    a += fmaf(nd * nd, h[(size_t)d * 64 + lane], bias[lane]);
    float m = a;
    #pragma unroll
    for (int off = 32; off; off >>= 1) m = fmaxf(m, __shfl_xor(m, off, 64));
    float ex = expf(a - m);
    float ssum = ex;
    #pragma unroll
    for (int off = 32; off; off >>= 1) ssum += __shfl_xor(ssum, off, 64);
    out[(size_t)d * 64 + lane] = ex / ssum;
}

extern "C" void kernel_launch(void* const* d_in, const int* in_sizes, int n_in,
                              void* d_out, int out_size, void* d_ws, size_t ws_size,
                              hipStream_t stream) {
    const float* x  = (const float*)d_in[0];
    const int*   ei = (const int*)d_in[1];
    const float* W1 = (const float*)d_in[2];
    const float* b1 = (const float*)d_in[3];
    const float* W2 = (const float*)d_in[4];
    const float* b2 = (const float*)d_in[5];
    float* out = (float*)d_out;

    const int N = in_sizes[0] / K_DIM;     // 100000
    const int E = in_sizes[1] / 2;         // 1600000
    const int nper = (N + 7) / 8;          // dst range per XCD bucket

    // Workspace layout (peak ~85 MB)
    size_t o = 0;
    char* base = (char*)d_ws;
    auto alloc = [&](size_t elems) {
        void* p = base + o;
        o += (elems * 4 + 1023) & ~(size_t)1023;
        return p;
    };
    const int nb_n = (N + 255) / 256;
    int*   deg    = (int*)  alloc(N);
    int*   rowptr = (int*)  alloc(N + 1);
    int*   cursor = (int*)  alloc(N);
    float* norm   = (float*)alloc(N);
    int*   bsum   = (int*)  alloc(nb_n);
    int*   csr    = (int*)  alloc(E);
    float* bufA   = (float*)alloc((size_t)N * 64);   // h1-half, then h2
    float* agg1   = (float*)alloc((size_t)N * 128);

    const int nb_e8 = ((E + 255) / 256) * 8;   // x8 for XCD range buckets
    const int nb_g = (N + 3) / 4;          // 4 waves/block, 1 wave per node
    const int nb_m = (N + 63) / 64;        // gemm row tiles

    zero_int<<<nb_n, 256, 0, stream>>>(deg, N);
    deg_count_x<<<nb_e8, 256, 0, stream>>>(ei + E, E, nper, deg);
    block_sums<<<nb_n, 256, 0, stream>>>(deg, N, bsum);
    scan_bsums<<<1, 1024, 0, stream>>>(bsum, nb_n, rowptr, N);
    scan_write<<<nb_n, 256, 0, stream>>>(deg, bsum, N, rowptr, cursor, norm);
    fill_csr_x<<<nb_e8, 256, 0, stream>>>(ei, E, nper, cursor, csr);

    // Layer 1, half 0 (cols 0..63)
    gemm64<128><<<nb_m, 256, 0, stream>>>(x, W1, bufA, N);
    gather_relu<<<nb_g, 256, 0, stream>>>(rowptr, csr, norm, bufA, b1, agg1, N);
    // Layer 1, half 1 (cols 64..127)
    gemm64<128><<<nb_m, 256, 0, stream>>>(x, W1 + 64, bufA, N);
    gather_relu<<<nb_g, 256, 0, stream>>>(rowptr, csr, norm, bufA, b1 + 64, agg1 + 64, N);

    // Layer 2
    gemm64<64><<<nb_m, 256, 0, stream>>>(agg1, W2, bufA, N);
    gather_softmax<<<nb_g, 256, 0, stream>>>(rowptr, csr, norm, bufA, b2, out, N);
}

// Round 6
// 455.975 us; speedup vs baseline: 6.1233x; 1.1325x over previous
//
#include <hip/hip_runtime.h>
#include <hip/hip_bf16.h>
#include <hip/hip_fp16.h>

// GCN: out = softmax( GCNConv2( relu( GCNConv1(x) ) ) )
// GCNConv(x) = D^-1/2 (A+I) D^-1/2 (x W) + b
//
// Round 6:
//  (a) Premultiplied activations: GEMM epilogue writes h'[r] = norm[r]*h[r];
//      gather becomes agg = nd*(sum h'[s] + h'[d]) + bias. Kills the per-edge
//      norm[s] gather and halves the shfl broadcasts (VALUBusy was 47%).
//  (b) h1' stored fp16 [N x 128]; layer-1 aggregation in ONE pass (lane loads
//      half2 = 2 cols). Same 256 B/row line footprint as one fp32 64-col pass
//      -> layer-1 beyond-L2 fetch halves (390 -> ~195 MB). h2 stays fp32.
//  (c) absmax has sat at the 2^-13 comparison floor for 4 rounds; fp16-h1
//      contributes ~4e-5 at the output - well inside the 5.18e-4 threshold.

#define K_DIM 128

__global__ __launch_bounds__(256) void zero_int(int* p, int n) {
    int i = blockIdx.x * 256 + threadIdx.x;
    if (i < n) p[i] = 0;
}

// XCD-bucketed degree count: block handles dst range (blockIdx&7).
__global__ __launch_bounds__(256) void deg_count_x(const int* __restrict__ dst, int E,
                                                   int nper, int* __restrict__ deg) {
    const int r = blockIdx.x & 7;
    const int e = (blockIdx.x >> 3) * 256 + threadIdx.x;
    if (e >= E) return;
    const int d = dst[e];
    if ((unsigned)(d - r * nper) < (unsigned)nper) atomicAdd(&deg[d], 1);
}

// ---- parallel exclusive scan of deg (N elements) ----
__global__ __launch_bounds__(256) void block_sums(const int* __restrict__ deg, int n,
                                                  int* __restrict__ bsum) {
    const int i = blockIdx.x * 256 + threadIdx.x;
    int v = (i < n) ? deg[i] : 0;
    #pragma unroll
    for (int off = 32; off; off >>= 1) v += __shfl_xor(v, off, 64);
    __shared__ int ws[4];
    const int lane = threadIdx.x & 63, wid = threadIdx.x >> 6;
    if (lane == 0) ws[wid] = v;
    __syncthreads();
    if (threadIdx.x == 0) bsum[blockIdx.x] = ws[0] + ws[1] + ws[2] + ws[3];
}

__global__ __launch_bounds__(1024) void scan_bsums(int* __restrict__ bsum, int nb,
                                                   int* __restrict__ rowptr, int n) {
    __shared__ int part[1024];
    const int t = threadIdx.x;
    const int chunk = (nb + 1023) >> 10;
    const int s = t * chunk;
    const int e = (s + chunk < nb) ? (s + chunk) : nb;
    int sum = 0;
    for (int i = s; i < e; ++i) sum += bsum[i];
    part[t] = sum;
    __syncthreads();
    for (int off = 1; off < 1024; off <<= 1) {
        int u = (t >= off) ? part[t - off] : 0;
        __syncthreads();
        part[t] += u;
        __syncthreads();
    }
    int run = part[t] - sum;
    for (int i = s; i < e; ++i) { int v = bsum[i]; bsum[i] = run; run += v; }
    if (t == 1023) rowptr[n] = part[1023];     // == E
}

__global__ __launch_bounds__(256) void scan_write(const int* __restrict__ deg,
                                                  const int* __restrict__ bsum, int n,
                                                  int* __restrict__ rowptr,
                                                  int* __restrict__ cursor,
                                                  float* __restrict__ norm) {
    const int i = blockIdx.x * 256 + threadIdx.x;
    const int lane = threadIdx.x & 63, wid = threadIdx.x >> 6;
    const int v = (i < n) ? deg[i] : 0;
    int inc = v;
    #pragma unroll
    for (int off = 1; off < 64; off <<= 1) {
        int u = __shfl_up(inc, off, 64);
        if (lane >= off) inc += u;
    }
    __shared__ int wsum[4];
    if (lane == 63) wsum[wid] = inc;
    __syncthreads();
    int woff = 0;
    for (int w = 0; w < wid; ++w) woff += wsum[w];
    if (i < n) {
        const int excl = bsum[blockIdx.x] + woff + inc - v;
        rowptr[i] = excl;
        cursor[i] = excl;
        norm[i] = rsqrtf((float)(v + 1));      // +1 self-loop
    }
}

// XCD-bucketed CSR fill.
__global__ __launch_bounds__(256) void fill_csr_x(const int* __restrict__ ei, int E,
                                                  int nper,
                                                  int* __restrict__ cursor,
                                                  int* __restrict__ csr_src) {
    const int r = blockIdx.x & 7;
    const int e = (blockIdx.x >> 3) * 256 + threadIdx.x;
    if (e >= E) return;
    const int d = ei[E + e];
    if ((unsigned)(d - r * nper) < (unsigned)nper) {
        const int s = ei[e];
        const int slot = atomicAdd(&cursor[d], 1);
        csr_src[slot] = s;
    }
}

// Tiled fp32 GEMM, 64-col output, premultiplied epilogue:
//   H'[row, colOff + c] = norm[row] * (A[row,:] @ W[:,c])
// HALF_OUT: store fp16 into __half* H with row stride ldh; else fp32.
template<int LDW, bool HALF_OUT>
__global__ __launch_bounds__(256) void gemm64(
    const float* __restrict__ A, const float* __restrict__ W,
    const float* __restrict__ norm,
    void* __restrict__ Hout, int ldh, int colOff, int nrows)
{
    __shared__ float Ast[64 * 128];   // [row][k], float4-slot XOR swizzle
    __shared__ float Bst[128 * 64];   // [k][col], natural

    const int tid = threadIdx.x;
    const int tx = tid & 15;
    const int ty = tid >> 4;
    const int row0 = blockIdx.x * 64;

    {   // stage A
        const int kq = tid & 31;
        const int r  = tid >> 5;
        #pragma unroll
        for (int p = 0; p < 8; ++p) {
            int rr = r + p * 8;
            int grow = row0 + rr;
            if (grow > nrows - 1) grow = nrows - 1;
            float4 v = *(const float4*)&A[(size_t)grow * K_DIM + kq * 4];
            *(float4*)&Ast[rr * 128 + 4 * (kq ^ (rr & 7))] = v;
        }
    }
    {   // stage B
        const int cq = tid & 15;
        const int kr = tid >> 4;
        #pragma unroll
        for (int p = 0; p < 8; ++p) {
            int k = kr + p * 16;
            *(float4*)&Bst[k * 64 + cq * 4] = *(const float4*)&W[(size_t)k * LDW + cq * 4];
        }
    }
    __syncthreads();

    float acc[4][4] = {};
    #pragma unroll 2
    for (int k0 = 0; k0 < 128; k0 += 4) {
        float4 b[4];
        #pragma unroll
        for (int kk = 0; kk < 4; ++kk)
            b[kk] = *(const float4*)&Bst[(k0 + kk) * 64 + tx * 4];
        #pragma unroll
        for (int i = 0; i < 4; ++i) {
            const int rr = ty * 4 + i;
            float4 a = *(const float4*)&Ast[rr * 128 + 4 * ((k0 >> 2) ^ (rr & 7))];
            #pragma unroll
            for (int j = 0; j < 4; ++j) {
                acc[i][j] = fmaf(a.x, ((const float*)&b[0])[j], acc[i][j]);
                acc[i][j] = fmaf(a.y, ((const float*)&b[1])[j], acc[i][j]);
                acc[i][j] = fmaf(a.z, ((const float*)&b[2])[j], acc[i][j]);
                acc[i][j] = fmaf(a.w, ((const float*)&b[3])[j], acc[i][j]);
            }
        }
    }

    #pragma unroll
    for (int i = 0; i < 4; ++i) {
        int row = row0 + ty * 4 + i;
        if (row < nrows) {
            const float nr = norm[row];
            if (HALF_OUT) {
                __half2* hp = (__half2*)Hout + ((size_t)row * ldh + colOff + tx * 4) / 2;
                hp[0] = __floats2half2_rn(acc[i][0] * nr, acc[i][1] * nr);
                hp[1] = __floats2half2_rn(acc[i][2] * nr, acc[i][3] * nr);
            } else {
                float4 o = make_float4(acc[i][0] * nr, acc[i][1] * nr,
                                       acc[i][2] * nr, acc[i][3] * nr);
                *(float4*)((float*)Hout + (size_t)row * ldh + colOff + tx * 4) = o;
            }
        }
    }
}

// Layer-1 aggregation, ONE pass over 128 fp16 cols (lane owns cols 2L,2L+1):
//   agg[d,:] = relu( nd * (sum_e h'[s_e,:] + h'[d,:]) + bias )
// h' is premultiplied by norm[src]; plain adds in the inner loop.
__global__ __launch_bounds__(256) void gather_relu_f16(
    const int* __restrict__ rowptr, const int* __restrict__ csr_src,
    const float* __restrict__ norm, const __half* __restrict__ h,
    const float* __restrict__ bias, float* __restrict__ agg, int n)
{
    const int lane = threadIdx.x & 63;
    const int w = threadIdx.x >> 6;
    const int d = blockIdx.x * 4 + w;
    if (d >= n) return;
    const __half2* hp = (const __half2*)h;   // row stride 64 half2

    float2 a0 = {0.f, 0.f}, a1 = {0.f, 0.f}, a2 = {0.f, 0.f}, a3 = {0.f, 0.f};
    const int jb = rowptr[d], je = rowptr[d + 1];
    for (int j0 = jb; j0 < je; j0 += 64) {
        const int cnt = (je - j0 < 64) ? (je - j0) : 64;
        int sidx = 0;
        if (lane < cnt) sidx = csr_src[j0 + lane];
        int t = 0;
        for (; t + 3 < cnt; t += 4) {
            const int s0 = __shfl(sidx, t, 64);
            const int s1 = __shfl(sidx, t + 1, 64);
            const int s2 = __shfl(sidx, t + 2, 64);
            const int s3 = __shfl(sidx, t + 3, 64);
            const float2 v0 = __half22float2(hp[(size_t)s0 * 64 + lane]);
            const float2 v1 = __half22float2(hp[(size_t)s1 * 64 + lane]);
            const float2 v2 = __half22float2(hp[(size_t)s2 * 64 + lane]);
            const float2 v3 = __half22float2(hp[(size_t)s3 * 64 + lane]);
            a0.x += v0.x; a0.y += v0.y;
            a1.x += v1.x; a1.y += v1.y;
            a2.x += v2.x; a2.y += v2.y;
            a3.x += v3.x; a3.y += v3.y;
        }
        for (; t < cnt; ++t) {
            const int s0 = __shfl(sidx, t, 64);
            const float2 v0 = __half22float2(hp[(size_t)s0 * 64 + lane]);
            a0.x += v0.x; a0.y += v0.y;
        }
    }
    const float2 sv = __half22float2(hp[(size_t)d * 64 + lane]);   // self (premult)
    const float nd = norm[d];
    float sx = (a0.x + a1.x) + (a2.x + a3.x) + sv.x;
    float sy = (a0.y + a1.y) + (a2.y + a3.y) + sv.y;
    float2 o;
    o.x = fmaxf(fmaf(nd, sx, bias[2 * lane]), 0.f);
    o.y = fmaxf(fmaf(nd, sy, bias[2 * lane + 1]), 0.f);
    ((float2*)agg)[(size_t)d * 64 + lane] = o;
}

// Layer-2 aggregation + row softmax; h' fp32 premultiplied, 64 cols = 64 lanes.
__global__ __launch_bounds__(256) void gather_softmax(
    const int* __restrict__ rowptr, const int* __restrict__ csr_src,
    const float* __restrict__ norm, const float* __restrict__ h,
    const float* __restrict__ bias, float* __restrict__ out, int n)
{
    const int lane = threadIdx.x & 63;
    const int w = threadIdx.x >> 6;
    const int d = blockIdx.x * 4 + w;
    if (d >= n) return;

    float a0 = 0.f, a1 = 0.f, a2 = 0.f, a3 = 0.f;
    const int jb = rowptr[d], je = rowptr[d + 1];
    for (int j0 = jb; j0 < je; j0 += 64) {
        const int cnt = (je - j0 < 64) ? (je - j0) : 64;
        int sidx = 0;
        if (lane < cnt) sidx = csr_src[j0 + lane];
        int t = 0;
        for (; t + 3 < cnt; t += 4) {
            const int s0 = __shfl(sidx, t, 64);
            const int s1 = __shfl(sidx, t + 1, 64);
            const int s2 = __shfl(sidx, t + 2, 64);
            const int s3 = __shfl(sidx, t + 3, 64);
            a0 += h[(size_t)s0 * 64 + lane];
            a1 += h[(size_t)s1 * 64 + lane];
            a2 += h[(size_t)s2 * 64 + lane];
            a3 += h[(size_t)s3 * 64 + lane];
        }
        for (; t < cnt; ++t) {
            const int s0 = __shfl(sidx, t, 64);
            a0 += h[(size_t)s0 * 64 + lane];
        }
    }
    const float nd = norm[d];
    float a = fmaf(nd, (a0 + a1) + (a2 + a3) + h[(size_t)d * 64 + lane], bias[lane]);
    float m = a;
    #pragma unroll
    for (int off = 32; off; off >>= 1) m = fmaxf(m, __shfl_xor(m, off, 64));
    float ex = expf(a - m);
    float ssum = ex;
    #pragma unroll
    for (int off = 32; off; off >>= 1) ssum += __shfl_xor(ssum, off, 64);
    out[(size_t)d * 64 + lane] = ex / ssum;
}

extern "C" void kernel_launch(void* const* d_in, const int* in_sizes, int n_in,
                              void* d_out, int out_size, void* d_ws, size_t ws_size,
                              hipStream_t stream) {
    const float* x  = (const float*)d_in[0];
    const int*   ei = (const int*)d_in[1];
    const float* W1 = (const float*)d_in[2];
    const float* b1 = (const float*)d_in[3];
    const float* W2 = (const float*)d_in[4];
    const float* b2 = (const float*)d_in[5];
    float* out = (float*)d_out;

    const int N = in_sizes[0] / K_DIM;     // 100000
    const int E = in_sizes[1] / 2;         // 1600000
    const int nper = (N + 7) / 8;          // dst range per XCD bucket

    // Workspace layout (peak ~85 MB)
    size_t o = 0;
    char* base = (char*)d_ws;
    auto alloc = [&](size_t elems) {       // elems in 4-byte units
        void* p = base + o;
        o += (elems * 4 + 1023) & ~(size_t)1023;
        return p;
    };
    const int nb_n = (N + 255) / 256;
    int*    deg    = (int*)   alloc(N);
    int*    rowptr = (int*)   alloc(N + 1);
    int*    cursor = (int*)   alloc(N);
    float*  norm   = (float*) alloc(N);
    int*    bsum   = (int*)   alloc(nb_n);
    int*    csr    = (int*)   alloc(E);
    void*   bufA   = alloc((size_t)N * 64);          // h1' fp16 [Nx128] == h2' fp32 [Nx64]
    float*  agg1   = (float*) alloc((size_t)N * 128);

    __half* h1h = (__half*)bufA;
    float*  h2f = (float*)bufA;

    const int nb_e8 = ((E + 255) / 256) * 8;   // x8 XCD range buckets
    const int nb_g = (N + 3) / 4;
    const int nb_m = (N + 63) / 64;

    zero_int<<<nb_n, 256, 0, stream>>>(deg, N);
    deg_count_x<<<nb_e8, 256, 0, stream>>>(ei + E, E, nper, deg);
    block_sums<<<nb_n, 256, 0, stream>>>(deg, N, bsum);
    scan_bsums<<<1, 1024, 0, stream>>>(bsum, nb_n, rowptr, N);
    scan_write<<<nb_n, 256, 0, stream>>>(deg, bsum, N, rowptr, cursor, norm);
    fill_csr_x<<<nb_e8, 256, 0, stream>>>(ei, E, nper, cursor, csr);

    // Layer 1: h1' = norm .* (x@W1), fp16 [N x 128], two 64-col passes
    gemm64<128, true><<<nb_m, 256, 0, stream>>>(x, W1,      norm, h1h, 128, 0,  N);
    gemm64<128, true><<<nb_m, 256, 0, stream>>>(x, W1 + 64, norm, h1h, 128, 64, N);
    // Single-pass aggregation over all 128 cols
    gather_relu_f16<<<nb_g, 256, 0, stream>>>(rowptr, csr, norm, h1h, b1, agg1, N);

    // Layer 2: h2' = norm .* (agg1@W2), fp32 [N x 64]
    gemm64<64, false><<<nb_m, 256, 0, stream>>>(agg1, W2, norm, h2f, 64, 0, N);
    gather_softmax<<<nb_g, 256, 0, stream>>>(rowptr, csr, norm, h2f, b2, out, N);
}